// Round 1
// baseline (64.608 us; speedup 1.0000x reference)
//
#include <hip/hip_runtime.h>

#define NNODE 25
#define NEDGE 64
#define HID   128
#define GB    32          // batches per block
#define BLOCK 256

__global__ __launch_bounds__(BLOCK) void gnn_fused(
    const float* __restrict__ x,        // [B][25][3]
    const int*   __restrict__ ei,       // [2][64]
    const float* __restrict__ W1l,      // [3][128]
    const float* __restrict__ W1r,      // [3][128]
    const float* __restrict__ b1,       // [128]
    const float* __restrict__ W2l,      // [128][128]
    const float* __restrict__ W2r,      // [128][128]
    const float* __restrict__ b2,       // [128]
    float* __restrict__ out,            // [B][128]
    int B)
{
  __shared__ float Mm[NNODE*NNODE];     // adjacency counts -> M = deg_inv * A
  __shared__ float cnt[NNODE];
  __shared__ float cvec[NNODE];
  __shared__ float xa[GB][NNODE][8];    // {agg0,agg1,agg2, x0,x1,x2, pad,pad}
  __shared__ float S[GB][2*HID];        // [s1 | s2] per batch

  const int tid = threadIdx.x;
  const int b0  = blockIdx.x * GB;

  // ---- build M and cvec from edge_index (cheap, redone per block) ----
  for (int i = tid; i < NNODE*NNODE; i += BLOCK) Mm[i] = 0.f;
  if (tid < NNODE) cnt[tid] = 0.f;
  __syncthreads();
  if (tid < NEDGE) {
    int s = ei[tid];
    int d = ei[NEDGE + tid];
    atomicAdd(&Mm[d*NNODE + s], 1.f);
    atomicAdd(&cnt[d], 1.f);
  }
  __syncthreads();
  for (int i = tid; i < NNODE*NNODE; i += BLOCK) {
    int n = i / NNODE;
    Mm[i] = Mm[i] / fmaxf(cnt[n], 1.f);
  }
  __syncthreads();
  if (tid < NNODE) {
    float acc = 0.f;
    for (int n = 0; n < NNODE; ++n) acc += Mm[n*NNODE + tid];
    cvec[tid] = acc * (1.f/(float)NNODE);
  }

  // ---- load x for this block's 32 batches into xa[..][4..6] ----
  for (int i = tid; i < GB*NNODE*3; i += BLOCK) {
    int g = i / (NNODE*3);
    int r = i - g*(NNODE*3);
    int n = r / 3, d = r - n*3;
    xa[g][n][4+d] = x[(size_t)(b0+g)*(NNODE*3) + r];
  }
  __syncthreads();

  // ---- aggregated x: xa[g][n][d] = sum_m M[n][m] * x[g][m][d] ----
  for (int i = tid; i < GB*NNODE*3; i += BLOCK) {
    int g = i / (NNODE*3);
    int r = i - g*(NNODE*3);
    int n = r / 3, d = r - n*3;
    float acc = 0.f;
    for (int m = 0; m < NNODE; ++m)
      acc += Mm[n*NNODE + m] * xa[g][m][4+d];
    xa[g][n][d] = acc;
  }
  __syncthreads();

  // ---- stage 1: h1 = relu(agg@W1l + x@W1r + b1); reduce to s1, s2 ----
  {
    const int c   = tid & (HID-1);
    const int grp = tid >> 7;           // 0 or 1 -> batch half
    const float w0 = W1l[0*HID + c], w1 = W1l[1*HID + c], w2 = W1l[2*HID + c];
    const float w3 = W1r[0*HID + c], w4 = W1r[1*HID + c], w5 = W1r[2*HID + c];
    const float bb = b1[c];
    for (int g = grp*(GB/2); g < (grp+1)*(GB/2); ++g) {
      float s1 = 0.f, s2 = 0.f;
      #pragma unroll 5
      for (int n = 0; n < NNODE; ++n) {
        const float4 p0 = *(const float4*)&xa[g][n][0];
        const float4 p1 = *(const float4*)&xa[g][n][4];
        float v = bb;
        v = fmaf(p0.x, w0, v); v = fmaf(p0.y, w1, v); v = fmaf(p0.z, w2, v);
        v = fmaf(p1.x, w3, v); v = fmaf(p1.y, w4, v); v = fmaf(p1.z, w5, v);
        v = fmaxf(v, 0.f);
        s1 = fmaf(cvec[n], v, s1);
        s2 += v;
      }
      S[g][c]       = s1;
      S[g][HID + c] = s2 * (1.f/(float)NNODE);
    }
  }
  __syncthreads();

  // ---- stage 2: out = s1@W2l + s2@W2r + b2 (register-tiled fp32 GEMM) ----
  {
    const int o    = tid & (HID-1);
    const int half = tid >> 7;
    float acc[GB/2];
    #pragma unroll
    for (int i = 0; i < GB/2; ++i) acc[i] = 0.f;

    for (int k = 0; k < HID; k += 4) {
      const float wl0 = W2l[(k+0)*HID+o], wl1 = W2l[(k+1)*HID+o];
      const float wl2 = W2l[(k+2)*HID+o], wl3 = W2l[(k+3)*HID+o];
      const float wr0 = W2r[(k+0)*HID+o], wr1 = W2r[(k+1)*HID+o];
      const float wr2 = W2r[(k+2)*HID+o], wr3 = W2r[(k+3)*HID+o];
      #pragma unroll
      for (int i = 0; i < GB/2; ++i) {
        const int g = half*(GB/2) + i;
        const float4 sa = *(const float4*)&S[g][k];
        const float4 sb = *(const float4*)&S[g][HID+k];
        acc[i] = fmaf(sa.x, wl0, acc[i]); acc[i] = fmaf(sa.y, wl1, acc[i]);
        acc[i] = fmaf(sa.z, wl2, acc[i]); acc[i] = fmaf(sa.w, wl3, acc[i]);
        acc[i] = fmaf(sb.x, wr0, acc[i]); acc[i] = fmaf(sb.y, wr1, acc[i]);
        acc[i] = fmaf(sb.z, wr2, acc[i]); acc[i] = fmaf(sb.w, wr3, acc[i]);
      }
    }
    const float bo = b2[o];
    #pragma unroll
    for (int i = 0; i < GB/2; ++i) {
      const int g = half*(GB/2) + i;
      out[(size_t)(b0+g)*HID + o] = acc[i] + bo;
    }
  }
}

extern "C" void kernel_launch(void* const* d_in, const int* in_sizes, int n_in,
                              void* d_out, int out_size, void* d_ws, size_t ws_size,
                              hipStream_t stream) {
  (void)n_in; (void)out_size; (void)d_ws; (void)ws_size;
  const float* x   = (const float*)d_in[0];
  const int*   ei  = (const int*)  d_in[1];
  const float* W1l = (const float*)d_in[2];
  const float* W1r = (const float*)d_in[3];
  const float* b1  = (const float*)d_in[4];
  const float* W2l = (const float*)d_in[5];
  const float* W2r = (const float*)d_in[6];
  const float* b2  = (const float*)d_in[7];
  float* out = (float*)d_out;

  const int B = in_sizes[0] / (NNODE*3);   // 16384
  dim3 grid(B / GB);
  gnn_fused<<<grid, BLOCK, 0, stream>>>(x, ei, W1l, W1r, b1, W2l, W2r, b2, out, B);
}

// Round 2
// 34.158 us; speedup vs baseline: 1.8915x; 1.8915x over previous
//
#include <hip/hip_runtime.h>
#include <hip/hip_bf16.h>

#define NNODE 25
#define NEDGE 64
#define HID   128
#define GB    16          // batches per block
#define BLOCK 256
#define KTOT  256         // 2*HID (concat [s1|s2] / [W2l;W2r])
#define SPAD  264         // S row stride in bf16 elems (pad: 132 dwords == 4 mod 32)

typedef __attribute__((ext_vector_type(8))) short short8;
typedef __attribute__((ext_vector_type(4))) float f32x4;

__device__ inline unsigned short f2bf(float f) {
  __hip_bfloat16 h = __float2bfloat16(f);
  unsigned short u; __builtin_memcpy(&u, &h, 2); return u;
}

// ---- precompute Wt[o][k] = bf16(W2cat[k][o]), o<128, k<256 ----
__global__ __launch_bounds__(256) void prep_wt(
    const float* __restrict__ W2l, const float* __restrict__ W2r,
    unsigned short* __restrict__ Wt)
{
  int i = blockIdx.x * 256 + threadIdx.x;        // [0, 32768)
  if (i >= HID * KTOT) return;
  int o = i >> 8;
  int k = i & 255;
  float v = (k < HID) ? W2l[k * HID + o] : W2r[(k - HID) * HID + o];
  Wt[o * KTOT + k] = f2bf(v);
}

__global__ __launch_bounds__(BLOCK, 4) void gnn_fused(
    const float* __restrict__ x,        // [B][25][3]
    const int*   __restrict__ ei,       // [2][64] (int32 on device)
    const float* __restrict__ W1l,      // [3][128]
    const float* __restrict__ W1r,      // [3][128]
    const float* __restrict__ b1,       // [128]
    const float* __restrict__ W2l,      // [128][128] (fallback path)
    const float* __restrict__ W2r,      // [128][128] (fallback path)
    const float* __restrict__ b2,       // [128]
    const unsigned short* __restrict__ Wt,  // [128][256] bf16, may be null
    float* __restrict__ out)            // [B][128]
{
  __shared__ float Mm[NNODE*NNODE];
  __shared__ float cnt[NNODE];
  __shared__ float cvec[NNODE];
  __shared__ __align__(16) float xa[GB][NNODE][8];     // [0..2]=agg [4..6]=x
  __shared__ __align__(16) unsigned short Sbf[GB][SPAD];

  const int tid  = threadIdx.x;
  const int b0   = blockIdx.x * GB;
  const int wave = tid >> 6;
  const int lane = tid & 63;

  // ---- init + build adjacency counts, load x ----
  for (int i = tid; i < NNODE*NNODE; i += BLOCK) Mm[i] = 0.f;
  if (tid < NNODE) cnt[tid] = 0.f;
  __syncthreads();
  if (tid < NEDGE) {
    int s = ei[tid], d = ei[NEDGE + tid];
    atomicAdd(&Mm[d*NNODE + s], 1.f);
    atomicAdd(&cnt[d], 1.f);
  }
  for (int i = tid; i < GB*NNODE*3; i += BLOCK) {
    int g = i / 75;
    int r = i - g*75;
    int n = r / 3, d = r - n*3;
    xa[g][n][4+d] = x[(size_t)b0*75 + i];
  }
  __syncthreads();

  // ---- normalize rows of M by degree ----
  for (int i = tid; i < NNODE*NNODE; i += BLOCK) {
    int n = i / NNODE;
    Mm[i] *= 1.f / fmaxf(cnt[n], 1.f);
  }
  __syncthreads();

  // ---- cvec[m] = (1/25) * sum_n M[n][m]  (layer-2 aggregation collapsed) ----
  if (tid < NNODE) {
    float acc = 0.f;
    for (int n = 0; n < NNODE; ++n) acc += Mm[n*NNODE + tid];
    cvec[tid] = acc * (1.f/25.f);
  }

  // ---- agg[g][n][d] = sum_m M[n][m] * x[g][m][d] ----
  for (int p = tid; p < GB*NNODE; p += BLOCK) {
    int g = p / NNODE, n = p - g*NNODE;
    float a0 = 0.f, a1 = 0.f, a2 = 0.f;
    #pragma unroll 5
    for (int m = 0; m < NNODE; ++m) {
      float w = Mm[n*NNODE + m];
      float4 xv = *(const float4*)&xa[g][m][4];
      a0 = fmaf(w, xv.x, a0);
      a1 = fmaf(w, xv.y, a1);
      a2 = fmaf(w, xv.z, a2);
    }
    xa[g][n][0] = a0; xa[g][n][1] = a1; xa[g][n][2] = a2;
  }
  __syncthreads();

  // ---- stage 1: wave w owns g in [4w,4w+4), lane owns channels {l, l+64} ----
  {
    const int c = lane;
    const float wl0a = W1l[0*HID+c],    wl1a = W1l[1*HID+c],    wl2a = W1l[2*HID+c];
    const float wr0a = W1r[0*HID+c],    wr1a = W1r[1*HID+c],    wr2a = W1r[2*HID+c];
    const float wl0b = W1l[0*HID+c+64], wl1b = W1l[1*HID+c+64], wl2b = W1l[2*HID+c+64];
    const float wr0b = W1r[0*HID+c+64], wr1b = W1r[1*HID+c+64], wr2b = W1r[2*HID+c+64];
    const float bba = b1[c], bbb = b1[c+64];
    for (int gi = 0; gi < GB/4; ++gi) {
      const int g = wave*(GB/4) + gi;
      float s1a = 0.f, s2a = 0.f, s1b = 0.f, s2b = 0.f;
      #pragma unroll 5
      for (int n = 0; n < NNODE; ++n) {
        const float4 pa = *(const float4*)&xa[g][n][0];
        const float4 pb = *(const float4*)&xa[g][n][4];
        const float cv = cvec[n];
        float va = bba, vb = bbb;
        va = fmaf(pa.x, wl0a, va); vb = fmaf(pa.x, wl0b, vb);
        va = fmaf(pa.y, wl1a, va); vb = fmaf(pa.y, wl1b, vb);
        va = fmaf(pa.z, wl2a, va); vb = fmaf(pa.z, wl2b, vb);
        va = fmaf(pb.x, wr0a, va); vb = fmaf(pb.x, wr0b, vb);
        va = fmaf(pb.y, wr1a, va); vb = fmaf(pb.y, wr1b, vb);
        va = fmaf(pb.z, wr2a, va); vb = fmaf(pb.z, wr2b, vb);
        va = fmaxf(va, 0.f); vb = fmaxf(vb, 0.f);
        s1a = fmaf(cv, va, s1a); s1b = fmaf(cv, vb, s1b);
        s2a += va; s2b += vb;
      }
      Sbf[g][c]        = f2bf(s1a);
      Sbf[g][c+64]     = f2bf(s1b);
      Sbf[g][HID+c]    = f2bf(s2a * (1.f/25.f));
      Sbf[g][HID+c+64] = f2bf(s2b * (1.f/25.f));
    }
  }
  __syncthreads();

  // ---- stage 2: out[16x128] = S[16x256] @ Wcat[256x128] via bf16 MFMA ----
  {
    const int kg = lane >> 4;          // k-group 0..3
    const int r  = lane & 15;          // row-of-A / col-of-B index
    const int n0 = wave * 32;          // this wave's 32 output cols
    f32x4 acc0 = {0.f,0.f,0.f,0.f};
    f32x4 acc1 = {0.f,0.f,0.f,0.f};

    if (Wt) {
      const unsigned short* WtA = Wt + (size_t)(n0 + r)      * KTOT;
      const unsigned short* WtB = Wt + (size_t)(n0 + 16 + r) * KTOT;
      #pragma unroll 2
      for (int kt = 0; kt < 8; ++kt) {
        const int kb = kt*32 + kg*8;
        short8 a  = *(const short8*)&Sbf[r][kb];
        short8 bA = *(const short8*)&WtA[kb];
        short8 bB = *(const short8*)&WtB[kb];
        acc0 = __builtin_amdgcn_mfma_f32_16x16x32_bf16(a, bA, acc0, 0, 0, 0);
        acc1 = __builtin_amdgcn_mfma_f32_16x16x32_bf16(a, bB, acc1, 0, 0, 0);
      }
    } else {
      // fallback: gather W2 fp32 and convert in-register
      const int colA = n0 + r, colB = n0 + 16 + r;
      #pragma unroll 2
      for (int kt = 0; kt < 8; ++kt) {
        const int kb = kt*32 + kg*8;
        const float* Wsrc = (kt < 4) ? W2l : W2r;
        const int kk = (kt < 4) ? kb : kb - HID;
        short8 a = *(const short8*)&Sbf[r][kb];
        short8 bA, bB;
        #pragma unroll
        for (int j = 0; j < 8; ++j) {
          bA[j] = (short)f2bf(Wsrc[(kk+j)*HID + colA]);
          bB[j] = (short)f2bf(Wsrc[(kk+j)*HID + colB]);
        }
        acc0 = __builtin_amdgcn_mfma_f32_16x16x32_bf16(a, bA, acc0, 0, 0, 0);
        acc1 = __builtin_amdgcn_mfma_f32_16x16x32_bf16(a, bB, acc1, 0, 0, 0);
      }
    }

    #pragma unroll
    for (int q = 0; q < 4; ++q) {
      const int row  = kg*4 + q;
      const int colA = n0 + r, colB = n0 + 16 + r;
      out[(size_t)(b0+row)*HID + colA] = acc0[q] + b2[colA];
      out[(size_t)(b0+row)*HID + colB] = acc1[q] + b2[colB];
    }
  }
}

extern "C" void kernel_launch(void* const* d_in, const int* in_sizes, int n_in,
                              void* d_out, int out_size, void* d_ws, size_t ws_size,
                              hipStream_t stream) {
  (void)n_in; (void)out_size;
  const float* x   = (const float*)d_in[0];
  const int*   ei  = (const int*)  d_in[1];
  const float* W1l = (const float*)d_in[2];
  const float* W1r = (const float*)d_in[3];
  const float* b1  = (const float*)d_in[4];
  const float* W2l = (const float*)d_in[5];
  const float* W2r = (const float*)d_in[6];
  const float* b2  = (const float*)d_in[7];
  float* out = (float*)d_out;

  const int B = in_sizes[0] / (NNODE*3);   // 16384
  unsigned short* Wt = nullptr;
  if (ws_size >= (size_t)HID * KTOT * sizeof(unsigned short)) {
    Wt = (unsigned short*)d_ws;
    prep_wt<<<dim3((HID*KTOT + 255)/256), dim3(256), 0, stream>>>(W2l, W2r, Wt);
  }
  gnn_fused<<<dim3(B / GB), dim3(BLOCK), 0, stream>>>(
      x, ei, W1l, W1r, b1, W2l, W2r, b2, Wt, out);
}

// Round 3
// 25.042 us; speedup vs baseline: 2.5800x; 1.3640x over previous
//
#include <hip/hip_runtime.h>
#include <hip/hip_bf16.h>

#define NNODE 25
#define HID   128
#define GB    16
#define BLOCK 256
#define KTOT  256
#define SPAD  264

typedef __attribute__((ext_vector_type(8))) short short8;
typedef __attribute__((ext_vector_type(4))) float f32x4;
typedef __attribute__((ext_vector_type(2))) float f32x2;

__device__ inline unsigned short f2bf(float f) {
  __hip_bfloat16 h = __float2bfloat16(f);
  unsigned short u; __builtin_memcpy(&u, &h, 2); return u;
}

// Xbf cell index: node n, batch g, 8 bf16 per cell; g XOR-swizzled to spread banks
#define XB(n, g) (((n)*GB + ((g) ^ ((n) & 15))) * 8)

// ---- precompute Wt[o][k] = bf16(W2cat[k][o]) ----
__global__ __launch_bounds__(256) void prep_wt(
    const float* __restrict__ W2l, const float* __restrict__ W2r,
    unsigned short* __restrict__ Wt)
{
  int i = blockIdx.x * 256 + threadIdx.x;
  if (i >= HID * KTOT) return;
  int o = i >> 8;
  int k = i & 255;
  float v = (k < HID) ? W2l[k * HID + o] : W2r[(k - HID) * HID + o];
  Wt[o * KTOT + k] = f2bf(v);
}

__global__ __launch_bounds__(BLOCK, 4) void gnn_fused(
    const float* __restrict__ x,        // [B][25][3]
    const int*   __restrict__ ei,       // [2][64]
    const float* __restrict__ W1l,      // [3][128]
    const float* __restrict__ W1r,      // [3][128]
    const float* __restrict__ b1,       // [128]
    const float* __restrict__ W2l,
    const float* __restrict__ W2r,
    const float* __restrict__ b2,       // [128]
    const unsigned short* __restrict__ Wt,  // [128][256] bf16 (may be null)
    float* __restrict__ out)            // [B][128]
{
  __shared__ float Mm[NNODE*NNODE];
  __shared__ float cnt[NNODE];
  __shared__ float cvecs[NNODE];
  __shared__ __align__(16) unsigned short Mtb[32][32];     // bf16 M[n][m], zero-pad
  __shared__ __align__(16) float Xt[3][GB][28];            // x[d][g][m], pad m 25..27
  __shared__ __align__(16) unsigned short Xbf[NNODE*GB*8]; // {agg0..2,x0..2,0,0}
  __shared__ __align__(16) unsigned short Sbf[GB][SPAD];   // [s1(128) | s2(128)]

  const int tid  = threadIdx.x;
  const int b0   = blockIdx.x * GB;
  const int wave = tid >> 6;
  const int lane = tid & 63;
  const int r    = lane & 15;
  const int kg   = lane >> 4;
  const f32x4 zz = {0.f, 0.f, 0.f, 0.f};

  // ---- phase 0: zero M counts, Mtb, Xt pad ----
  for (int i = tid; i < NNODE*NNODE; i += BLOCK) Mm[i] = 0.f;
  if (tid < NNODE) cnt[tid] = 0.f;
  for (int i = tid; i < 32*32; i += BLOCK) ((unsigned short*)Mtb)[i] = 0;
  if (tid < 3*GB*3) {           // Xt[d][g][25..27] = 0
    int d = tid / (GB*3), rm = tid % (GB*3);
    Xt[d][rm/3][25 + rm%3] = 0.f;
  }
  __syncthreads();

  // ---- phase 1: edge atomics + x load ----
  if (tid < 64) {
    int s = ei[tid], d = ei[64 + tid];
    atomicAdd(&Mm[d*NNODE + s], 1.f);
    atomicAdd(&cnt[d], 1.f);
  }
  for (int i = tid; i < GB*NNODE*3; i += BLOCK) {
    int g = i / 75, rm = i - g*75;
    int n = rm / 3, d = rm - n*3;
    float v = x[(size_t)b0*75 + i];
    Xt[d][g][n] = v;
    Xbf[XB(n, g) + 3 + d] = f2bf(v);
  }
  for (int p = tid; p < NNODE*GB; p += BLOCK) {   // zero k=6,7 slots
    int n = p >> 4, g = p & 15;
    *(unsigned int*)&Xbf[XB(n, g) + 6] = 0u;
  }
  __syncthreads();

  // ---- phase 2: normalize M, build bf16 Mtb ----
  for (int i = tid; i < NNODE*NNODE; i += BLOCK) {
    int n = i / NNODE;
    float v = Mm[i] / fmaxf(cnt[n], 1.f);
    Mm[i] = v;
    Mtb[n][i - n*NNODE] = f2bf(v);
  }
  __syncthreads();

  // ---- phase 3: agg via MFMA (waves 0-2, one d each); cvec (wave 3) ----
  if (wave < 3) {
    const int d = wave;
    short8 mb0 = *(const short8*)&Mtb[r][kg*8];        // B[k=m][col=n],  n=r
    short8 mb1 = *(const short8*)&Mtb[16 + r][kg*8];   // n=16+r (zero rows >=25)
    f32x4 x0 = *(const f32x4*)&Xt[d][r][kg*8];
    f32x4 x1 = *(const f32x4*)&Xt[d][r][kg*8 + 4];
    short8 af;
    af[0]=(short)f2bf(x0[0]); af[1]=(short)f2bf(x0[1]);
    af[2]=(short)f2bf(x0[2]); af[3]=(short)f2bf(x0[3]);
    af[4]=(short)f2bf(x1[0]); af[5]=(short)f2bf(x1[1]);
    af[6]=(short)f2bf(x1[2]); af[7]=(short)f2bf(x1[3]);
    f32x4 g0 = __builtin_amdgcn_mfma_f32_16x16x32_bf16(af, mb0, zz, 0, 0, 0);
    f32x4 g1 = __builtin_amdgcn_mfma_f32_16x16x32_bf16(af, mb1, zz, 0, 0, 0);
    #pragma unroll
    for (int q = 0; q < 4; ++q) {
      int g = kg*4 + q;                  // C row = batch
      Xbf[XB(r, g) + d] = f2bf(g0[q]);   // C col = node n = r
      if (r < 9) Xbf[XB(16 + r, g) + d] = f2bf(g1[q]);
    }
  } else {
    for (int m = lane; m < NNODE; m += 64) {
      float a = 0.f;
      for (int n = 0; n < NNODE; ++n) a += Mm[n*NNODE + m];
      cvecs[m] = a * (1.f/NNODE);
    }
  }
  __syncthreads();

  // ---- phase 4: stage 1 via MFMA, n-reduction in packed f32 ----
  {
    const int c0 = wave * 32;
    const int cA = c0 + r, cB = c0 + 16 + r;
    short8 bfA, bfB;
    #pragma unroll
    for (int j = 0; j < 8; ++j) {
      float va = 0.f, vb = 0.f;
      if (kg == 0) {
        if (j < 3)      { va = W1l[j*HID + cA];     vb = W1l[j*HID + cB]; }
        else if (j < 6) { va = W1r[(j-3)*HID + cA]; vb = W1r[(j-3)*HID + cB]; }
      }
      bfA[j] = (short)f2bf(va);
      bfB[j] = (short)f2bf(vb);
    }
    f32x2 bias; bias.x = b1[cA]; bias.y = b1[cB];
    f32x2 s1[4] = {}, s2[4] = {};
    for (int n = 0; n < NNODE; ++n) {
      short8 a = *(const short8*)&Xbf[XB(n, r)];   // A row = batch r
      f32x4 h0 = __builtin_amdgcn_mfma_f32_16x16x32_bf16(a, bfA, zz, 0, 0, 0);
      f32x4 h1 = __builtin_amdgcn_mfma_f32_16x16x32_bf16(a, bfB, zz, 0, 0, 0);
      const float cv = cvecs[n];
      const f32x2 cvv = {cv, cv};
      #pragma unroll
      for (int q = 0; q < 4; ++q) {
        f32x2 v; v.x = h0[q]; v.y = h1[q];
        v += bias;
        v.x = fmaxf(v.x, 0.f); v.y = fmaxf(v.y, 0.f);
        s1[q] += cvv * v;
        s2[q] += v;
      }
    }
    #pragma unroll
    for (int q = 0; q < 4; ++q) {
      int g = kg*4 + q;
      Sbf[g][cA]       = f2bf(s1[q].x);
      Sbf[g][cB]       = f2bf(s1[q].y);
      Sbf[g][HID + cA] = f2bf(s2[q].x * (1.f/NNODE));
      Sbf[g][HID + cB] = f2bf(s2[q].y * (1.f/NNODE));
    }
  }
  __syncthreads();

  // ---- phase 5: stage 2: out[16x128] = S[16x256] @ Wcat via MFMA ----
  {
    const int n0 = wave * 32;
    f32x4 acc0 = zz, acc1 = zz;

    if (Wt) {
      const unsigned short* WtA = Wt + (size_t)(n0 + r)      * KTOT;
      const unsigned short* WtB = Wt + (size_t)(n0 + 16 + r) * KTOT;
      #pragma unroll 2
      for (int kt = 0; kt < 8; ++kt) {
        const int kb = kt*32 + kg*8;
        short8 a  = *(const short8*)&Sbf[r][kb];
        short8 bA = *(const short8*)&WtA[kb];
        short8 bB = *(const short8*)&WtB[kb];
        acc0 = __builtin_amdgcn_mfma_f32_16x16x32_bf16(a, bA, acc0, 0, 0, 0);
        acc1 = __builtin_amdgcn_mfma_f32_16x16x32_bf16(a, bB, acc1, 0, 0, 0);
      }
    } else {
      const int colA = n0 + r, colB = n0 + 16 + r;
      #pragma unroll 2
      for (int kt = 0; kt < 8; ++kt) {
        const int kb = kt*32 + kg*8;
        const float* Wsrc = (kt < 4) ? W2l : W2r;
        const int kk = (kt < 4) ? kb : kb - HID;
        short8 a = *(const short8*)&Sbf[r][kb];
        short8 bA, bB;
        #pragma unroll
        for (int j = 0; j < 8; ++j) {
          bA[j] = (short)f2bf(Wsrc[(kk+j)*HID + colA]);
          bB[j] = (short)f2bf(Wsrc[(kk+j)*HID + colB]);
        }
        acc0 = __builtin_amdgcn_mfma_f32_16x16x32_bf16(a, bA, acc0, 0, 0, 0);
        acc1 = __builtin_amdgcn_mfma_f32_16x16x32_bf16(a, bB, acc1, 0, 0, 0);
      }
    }

    #pragma unroll
    for (int q = 0; q < 4; ++q) {
      const int row  = kg*4 + q;
      const int colA = n0 + r, colB = n0 + 16 + r;
      out[(size_t)(b0+row)*HID + colA] = acc0[q] + b2[colA];
      out[(size_t)(b0+row)*HID + colB] = acc1[q] + b2[colB];
    }
  }
}

extern "C" void kernel_launch(void* const* d_in, const int* in_sizes, int n_in,
                              void* d_out, int out_size, void* d_ws, size_t ws_size,
                              hipStream_t stream) {
  (void)n_in; (void)out_size;
  const float* x   = (const float*)d_in[0];
  const int*   ei  = (const int*)  d_in[1];
  const float* W1l = (const float*)d_in[2];
  const float* W1r = (const float*)d_in[3];
  const float* b1  = (const float*)d_in[4];
  const float* W2l = (const float*)d_in[5];
  const float* W2r = (const float*)d_in[6];
  const float* b2  = (const float*)d_in[7];
  float* out = (float*)d_out;

  const int B = in_sizes[0] / (NNODE*3);   // 16384
  unsigned short* Wt = nullptr;
  if (ws_size >= (size_t)HID * KTOT * sizeof(unsigned short)) {
    Wt = (unsigned short*)d_ws;
    prep_wt<<<dim3((HID*KTOT + 255)/256), dim3(256), 0, stream>>>(W2l, W2r, Wt);
  }
  gnn_fused<<<dim3(B / GB), dim3(BLOCK), 0, stream>>>(
      x, ei, W1l, W1r, b1, W2l, W2r, b2, Wt, out);
}